// Round 13
// baseline (308.503 us; speedup 1.0000x reference)
//
#include <hip/hip_runtime.h>
#include <hip/hip_bf16.h>
#include <math.h>

#define NEG_SLOPE 0.2f

typedef __attribute__((ext_vector_type(8))) __bf16 bf16x8;
typedef __attribute__((ext_vector_type(4))) float f32x4;

// ---------------- helpers ----------------
__device__ inline float lrelu(float v) { return v > 0.f ? v : NEG_SLOPE * v; }

__device__ inline unsigned short f2bf(float f) {
    __hip_bfloat16 h = __float2bfloat16(f);
    return *reinterpret_cast<unsigned short*>(&h);
}
__device__ inline float bf_lo(unsigned u) { return __uint_as_float(u << 16); }
__device__ inline float bf_hi(unsigned u) { return __uint_as_float(u & 0xffff0000u); }

__device__ inline void transpose_one(const float* __restrict__ in,
                                     unsigned short* __restrict__ out,
                                     int K, int N, int idx) {
    if (idx >= K * N) return;
    int n = idx / K, k = idx % K;
    out[(size_t)n * K + k] = f2bf(in[(size_t)k * N + n]);
}

// ---------------- fused preprocessing: x-cast + 4 transposes + degree count --------
__global__ __launch_bounds__(256) void preproc_kernel(
    const float* __restrict__ x, unsigned short* __restrict__ xbf, int n4,
    const float* __restrict__ W1, unsigned short* __restrict__ W1t,
    const float* __restrict__ W2, unsigned short* __restrict__ W2t,
    const float* __restrict__ W3, unsigned short* __restrict__ W3t,
    const float* __restrict__ Ws1, unsigned short* __restrict__ Ws1t,
    const int* __restrict__ ei, int E, int N, int* __restrict__ deg,
    int c0, int c1, int c2, int c3, int c4,
    int D, int HC, int C) {
    int b = blockIdx.x;
    int t = threadIdx.x;
    if (b < c0) {
        int i = b * 256 + t;
        if (i < n4) {
            float4 v = reinterpret_cast<const float4*>(x)[i];
            ushort4 o;
            o.x = f2bf(v.x); o.y = f2bf(v.y); o.z = f2bf(v.z); o.w = f2bf(v.w);
            reinterpret_cast<ushort4*>(xbf)[i] = o;
        }
        return;
    }
    b -= c0;
    if (b < c1) { transpose_one(W1, W1t, D, HC, b * 256 + t); return; }
    b -= c1;
    if (b < c2) { transpose_one(W2, W2t, HC, HC, b * 256 + t); return; }
    b -= c2;
    if (b < c3) { transpose_one(W3, W3t, HC, C, b * 256 + t); return; }
    b -= c3;
    if (b < c4) { transpose_one(Ws1, Ws1t, 128, 64, b * 256 + t); return; }
    b -= c4;
    {
        int e = b * 256 + t;
        if (e < E + N) {
            int dst = (e < E) ? ei[E + e] : (e - E);
            atomicAdd(&deg[dst], 1);
        }
    }
}

// ---------------- CSR scan ----------------
__global__ void scan_kernel(const int* __restrict__ deg, int* __restrict__ off, int N) {
    __shared__ int sums[1024];
    int tid = threadIdx.x;
    int chunk = (N + 1023) / 1024;
    int start = tid * chunk;
    int end = start + chunk; if (end > N) end = N;
    int s = 0;
#pragma unroll 4
    for (int i = start; i < end && i < N; i++) s += deg[i];
    sums[tid] = s;
    __syncthreads();
    for (int d = 1; d < 1024; d <<= 1) {
        int v = 0;
        if (tid >= d) v = sums[tid - d];
        __syncthreads();
        if (tid >= d) sums[tid] += v;
        __syncthreads();
    }
    int prefix = (tid == 0) ? 0 : sums[tid - 1];
    int run = prefix;
#pragma unroll 4
    for (int i = start; i < end && i < N; i++) { off[i] = run; run += deg[i]; }
    if (tid == 1023) off[N] = sums[1023];
}

// ---------------- bf16 MFMA GEMM (BM=64, BN=128, BK=64, XOR swizzle) + alpha --------
// Optionally prepends `scatBlocks` CSR-scatter blocks (independent work, fused to
// share one dispatch). XCD-aware decode: 4 col-tiles of one row-tile share an XCD.
template <int HEADS>
__global__ __launch_bounds__(256) void gemm_bf16_alpha(const unsigned short* __restrict__ A,
                                                       const unsigned short* __restrict__ Bt,
                                                       unsigned short* __restrict__ C,
                                                       int M, int N, int K, int rowTiles,
                                                       const float* __restrict__ a_src,
                                                       const float* __restrict__ a_dst,
                                                       float* __restrict__ alS,
                                                       float* __restrict__ alD,
                                                       int scatBlocks,
                                                       const int* __restrict__ ei, int E,
                                                       const int* __restrict__ off,
                                                       int* __restrict__ cursor,
                                                       int* __restrict__ csr_src) {
    __shared__ unsigned short Asl[64 * 64];    // 8 KB
    __shared__ unsigned short Bsl[128 * 64];   // 16 KB
    const int tid  = threadIdx.x;

    if (blockIdx.x < scatBlocks) {             // fused CSR scatter segment
        int e = blockIdx.x * 256 + tid;
        if (e < E + M) {
            int src, dst;
            if (e < E) { src = ei[e]; dst = ei[E + e]; }
            else       { src = dst = e - E; }
            int pos = off[dst] + atomicAdd(&cursor[dst], 1);
            csr_src[pos] = src;
        }
        return;
    }

    const int lane = tid & 63;
    const int wave = tid >> 6;

    int r, c;
    {
        int b = blockIdx.x - scatBlocks;
        int colTiles = N >> 7;
        if (colTiles == 4) {
            int mainRows = rowTiles & ~7;
            int mainBlocks = mainRows * 4;
            if (b < mainBlocks) {
                int xcd = b & 7;
                c = (b >> 3) & 3;
                r = (b >> 5) * 8 + xcd;
            } else {
                int idx = b - mainBlocks;
                r = mainRows + (idx >> 2);
                c = idx & 3;
            }
        } else { r = b; c = 0; }
    }
    const int rowBase = r * 64;
    const int colBase = c * 128;
    const int wm = (wave & 1) * 32;
    const int wn = (wave >> 1) * 64;
    const int q   = lane >> 4;
    const int l16 = lane & 15;

    const int r0 = tid >> 3;
    const int cg = (tid & 7) ^ (r0 & 7);

    f32x4 acc[2][4] = {};

    for (int k0 = 0; k0 < K; k0 += 64) {
#pragma unroll
        for (int it = 0; it < 2; it++) {       // A: 64 rows
            int s = it * 256 + tid;
            int rr = it * 32 + r0;
            int ga = rowBase + rr; if (ga >= M) ga = M - 1;
            const unsigned short* gpa = A + (size_t)ga * K + k0 + cg * 8;
            __builtin_amdgcn_global_load_lds(
                (const __attribute__((address_space(1))) void*)gpa,
                (__attribute__((address_space(3))) void*)&Asl[(size_t)s * 8],
                16, 0, 0);
        }
#pragma unroll
        for (int it = 0; it < 4; it++) {       // B: 128 rows
            int s = it * 256 + tid;
            int rr = it * 32 + r0;
            const unsigned short* gpb = Bt + (size_t)(colBase + rr) * K + k0 + cg * 8;
            __builtin_amdgcn_global_load_lds(
                (const __attribute__((address_space(1))) void*)gpb,
                (__attribute__((address_space(3))) void*)&Bsl[(size_t)s * 8],
                16, 0, 0);
        }
        __syncthreads();

#pragma unroll
        for (int kh = 0; kh < 2; kh++) {
            bf16x8 af[2], bfv[4];
#pragma unroll
            for (int mi = 0; mi < 2; mi++) {
                int row = wm + mi * 16 + l16;
                int ch = (kh * 4 + q) ^ (row & 7);
                af[mi] = *reinterpret_cast<const bf16x8*>(&Asl[row * 64 + ch * 8]);
            }
#pragma unroll
            for (int ni = 0; ni < 4; ni++) {
                int row = wn + ni * 16 + l16;
                int ch = (kh * 4 + q) ^ (row & 7);
                bfv[ni] = *reinterpret_cast<const bf16x8*>(&Bsl[row * 64 + ch * 8]);
            }
#pragma unroll
            for (int mi = 0; mi < 2; mi++)
#pragma unroll
                for (int ni = 0; ni < 4; ni++)
                    acc[mi][ni] = __builtin_amdgcn_mfma_f32_16x16x32_bf16(af[mi], bfv[ni], acc[mi][ni], 0, 0, 0);
        }
        __syncthreads();
    }

    const int hIdx = colBase >> 7;
    const float* asl = a_src + hIdx * 128;
    const float* adl = a_dst + hIdx * 128;
    float acoef[4], dcoef[4];
#pragma unroll
    for (int ni = 0; ni < 4; ni++) {
        int cl = wn + ni * 16 + l16;
        acoef[ni] = asl[cl];
        dcoef[ni] = adl[cl];
    }

    float2* red = reinterpret_cast<float2*>(Asl);
    const int half = wn >> 6;

#pragma unroll
    for (int mi = 0; mi < 2; mi++) {
#pragma unroll
        for (int rr = 0; rr < 4; rr++) {
            int lrow = wm + mi * 16 + q * 4 + rr;
            int grow = rowBase + lrow;
            bool ok = grow < M;
            float vs = 0.f, vd = 0.f;
#pragma unroll
            for (int ni = 0; ni < 4; ni++) {
                float hv = acc[mi][ni][rr];
                vs += hv * acoef[ni];
                vd += hv * dcoef[ni];
                if (ok) {
                    int gcol = colBase + wn + ni * 16 + l16;
                    C[(size_t)grow * N + gcol] = f2bf(hv);
                }
            }
#pragma unroll
            for (int d = 1; d < 16; d <<= 1) {
                vs += __shfl_xor(vs, d);
                vd += __shfl_xor(vd, d);
            }
            if (l16 == 0) red[lrow * 2 + half] = make_float2(vs, vd);
        }
    }
    __syncthreads();
    if (tid < 64) {
        int grow = rowBase + tid;
        if (grow < M) {
            float2 a = red[tid * 2 + 0];
            float2 b = red[tid * 2 + 1];
            alS[(size_t)grow * HEADS + hIdx] = a.x + b.x;
            alD[(size_t)grow * HEADS + hIdx] = a.y + b.y;
        }
    }
}

// ---------------- fused segment softmax + aggregate, wave/node ----------------------
// 16-lane subgroup stats; weight redistribution via wave-private LDS; consume is a
// fully-unrolled 3-set pipeline (8 gathers in flight before first consume).
// MODE 0: bf16 + relu. MODE 2: bf16 + bias (no relu).
template <int H, int C, int MODE>
__global__ __launch_bounds__(256) void gat_aggregate(const unsigned short* __restrict__ hb,
                                                     const float* __restrict__ alS,
                                                     const float* __restrict__ alD,
                                                     const int* __restrict__ off,
                                                     const int* __restrict__ csr_src,
                                                     const float* __restrict__ bias,
                                                     unsigned short* __restrict__ outbuf,
                                                     int N) {
    constexpr int HC = H * C;
    constexpr int PER = HC / 64;
    __shared__ int   sIdx[4][16];
    __shared__ float sW[4][64];

    int n = (blockIdx.x * blockDim.x + threadIdx.x) >> 6;
    int lane = threadIdx.x & 63;
    int wave = threadIdx.x >> 6;
    if (n >= N) return;
    int beg = off[n], end = off[n + 1];

    const int grp  = lane >> 4;
    const int slot = lane & 15;
    const int myh  = (H == 4) ? grp : 0;
    const float adh = alD[n * H + myh];
    const unsigned short* hbl = hb + (size_t)lane * PER;
    const float* sWrow = &sW[wave][grp * 16];

    float m = -1e30f, dn = 0.f;
    float acc0 = 0.f, acc1 = 0.f, acc2 = 0.f, acc3 = 0.f,
          acc4 = 0.f, acc5 = 0.f, acc6 = 0.f, acc7 = 0.f;

    for (int base = beg; base < end; base += 16) {
        int cnt = end - base; if (cnt > 16) cnt = 16;
        bool act = slot < cnt;
        int s_l = csr_src[act ? (base + slot) : base];
        float v = act ? lrelu(alS[s_l * H + myh] + adh) : -1e30f;

        float mc = v;
#pragma unroll
        for (int d = 1; d < 16; d <<= 1) mc = fmaxf(mc, __shfl_xor(mc, d));
        float pl = __expf(v - mc);              // inactive -> exactly 0
        float dc = pl;
#pragma unroll
        for (int d = 1; d < 16; d <<= 1) dc += __shfl_xor(dc, d);
        float nm = fmaxf(m, mc);
        float so = __expf(m - nm);
        float sc = __expf(mc - nm);
        dn = dn * so + dc * sc;
        m = nm;
        float wl = pl * sc;

        if (lane < 16) sIdx[wave][lane] = s_l;
        sW[wave][lane] = wl;

        acc0 *= so; acc1 *= so;
        if (PER == 8) {
            acc2 *= so; acc3 *= so; acc4 *= so; acc5 *= so;
            acc6 *= so; acc7 *= so;
        }

        int cntR = (cnt + 3) & ~3;             // 4, 8, 12, or 16

        if (PER == 8) {
            int4 sIa, sIb, sIc; float4 wva, wvb, wvc;
            uint4 a0, a1, a2, a3, b0, b1, b2, b3, c0, c1, c2, c3;
#define ISSUE8(SI, WV, B0, B1, B2, B3, G)                                        \
            { SI = *reinterpret_cast<const int4*>(&sIdx[wave][(G) * 4]);         \
              WV = *reinterpret_cast<const float4*>(&sWrow[(G) * 4]);            \
              B0 = *reinterpret_cast<const uint4*>(hbl + (size_t)SI.x * HC);     \
              B1 = *reinterpret_cast<const uint4*>(hbl + (size_t)SI.y * HC);     \
              B2 = *reinterpret_cast<const uint4*>(hbl + (size_t)SI.z * HC);     \
              B3 = *reinterpret_cast<const uint4*>(hbl + (size_t)SI.w * HC); }
#define CONS1(B, W)                                                              \
            { acc0 += bf_lo(B.x) * W; acc1 += bf_hi(B.x) * W;                    \
              acc2 += bf_lo(B.y) * W; acc3 += bf_hi(B.y) * W;                    \
              acc4 += bf_lo(B.z) * W; acc5 += bf_hi(B.z) * W;                    \
              acc6 += bf_lo(B.w) * W; acc7 += bf_hi(B.w) * W; }
#define CONS48(WV, B0, B1, B2, B3)                                               \
            { CONS1(B0, WV.x) CONS1(B1, WV.y) CONS1(B2, WV.z) CONS1(B3, WV.w) }
            ISSUE8(sIa, wva, a0, a1, a2, a3, 0);
            if (cntR > 4)  ISSUE8(sIb, wvb, b0, b1, b2, b3, 1);
            CONS48(wva, a0, a1, a2, a3);
            if (cntR > 8)  ISSUE8(sIc, wvc, c0, c1, c2, c3, 2);
            if (cntR > 4)  CONS48(wvb, b0, b1, b2, b3);
            if (cntR > 12) ISSUE8(sIa, wva, a0, a1, a2, a3, 3);
            if (cntR > 8)  CONS48(wvc, c0, c1, c2, c3);
            if (cntR > 12) CONS48(wva, a0, a1, a2, a3);
#undef ISSUE8
#undef CONS1
#undef CONS48
        } else {
            int4 sIa, sIb, sIc; float4 wva, wvb, wvc;
            unsigned a0, a1, a2, a3, b0, b1, b2, b3, c0, c1, c2, c3;
#define ISSUE2(SI, WV, B0, B1, B2, B3, G)                                        \
            { SI = *reinterpret_cast<const int4*>(&sIdx[wave][(G) * 4]);         \
              WV = *reinterpret_cast<const float4*>(&sWrow[(G) * 4]);            \
              B0 = *reinterpret_cast<const unsigned*>(hbl + (size_t)SI.x * HC);  \
              B1 = *reinterpret_cast<const unsigned*>(hbl + (size_t)SI.y * HC);  \
              B2 = *reinterpret_cast<const unsigned*>(hbl + (size_t)SI.z * HC);  \
              B3 = *reinterpret_cast<const unsigned*>(hbl + (size_t)SI.w * HC); }
#define CONS42(WV, B0, B1, B2, B3)                                               \
            { acc0 += bf_lo(B0) * WV.x; acc1 += bf_hi(B0) * WV.x;                \
              acc0 += bf_lo(B1) * WV.y; acc1 += bf_hi(B1) * WV.y;                \
              acc0 += bf_lo(B2) * WV.z; acc1 += bf_hi(B2) * WV.z;                \
              acc0 += bf_lo(B3) * WV.w; acc1 += bf_hi(B3) * WV.w; }
            ISSUE2(sIa, wva, a0, a1, a2, a3, 0);
            if (cntR > 4)  ISSUE2(sIb, wvb, b0, b1, b2, b3, 1);
            CONS42(wva, a0, a1, a2, a3);
            if (cntR > 8)  ISSUE2(sIc, wvc, c0, c1, c2, c3, 2);
            if (cntR > 4)  CONS42(wvb, b0, b1, b2, b3);
            if (cntR > 12) ISSUE2(sIa, wva, a0, a1, a2, a3, 3);
            if (cntR > 8)  CONS42(wvc, c0, c1, c2, c3);
            if (cntR > 12) CONS42(wva, a0, a1, a2, a3);
#undef ISSUE2
#undef CONS42
        }
    }

    float invd = 1.f / dn;
    unsigned short* op = outbuf + (size_t)n * HC + lane * PER;
    const float* bp = bias + lane * PER;
    if (PER == 8) {
        float o0 = acc0 * invd + bp[0], o1 = acc1 * invd + bp[1];
        float o2 = acc2 * invd + bp[2], o3 = acc3 * invd + bp[3];
        float o4 = acc4 * invd + bp[4], o5 = acc5 * invd + bp[5];
        float o6 = acc6 * invd + bp[6], o7 = acc7 * invd + bp[7];
        if (MODE == 0) {
            o0 = fmaxf(o0, 0.f); o1 = fmaxf(o1, 0.f); o2 = fmaxf(o2, 0.f); o3 = fmaxf(o3, 0.f);
            o4 = fmaxf(o4, 0.f); o5 = fmaxf(o5, 0.f); o6 = fmaxf(o6, 0.f); o7 = fmaxf(o7, 0.f);
        }
        op[0] = f2bf(o0); op[1] = f2bf(o1); op[2] = f2bf(o2); op[3] = f2bf(o3);
        op[4] = f2bf(o4); op[5] = f2bf(o5); op[6] = f2bf(o6); op[7] = f2bf(o7);
    } else {
        float o0 = acc0 * invd + bp[0], o1 = acc1 * invd + bp[1];
        if (MODE == 0) { o0 = fmaxf(o0, 0.f); o1 = fmaxf(o1, 0.f); }
        op[0] = f2bf(o0); op[1] = f2bf(o1);
    }
}

// ---------------- MFMA risk head: sigmoid(relu(H3@Ws1+bs1)@Ws2+bs2) ----------------
__global__ __launch_bounds__(256) void head_mfma(const unsigned short* __restrict__ H3,
                                                 const unsigned short* __restrict__ W1t,
                                                 const float* __restrict__ bs1,
                                                 const float* __restrict__ Ws2,
                                                 const float* __restrict__ bs2,
                                                 float* __restrict__ out, int M) {
    __shared__ unsigned short Asl[128 * 128];  // 32 KB
    __shared__ unsigned short Bsl[64 * 128];   // 16 KB
    const int tid = threadIdx.x, lane = tid & 63, wave = tid >> 6;
    const int q = lane >> 4, l16 = lane & 15;
    const int rowBase = blockIdx.x * 128;
    const int r0 = tid >> 4;
    const int cg = (tid & 15) ^ (r0 & 7);

#pragma unroll
    for (int it = 0; it < 8; it++) {
        int s = it * 256 + tid;
        int r = it * 16 + r0;
        int ga = rowBase + r; if (ga >= M) ga = M - 1;
        const unsigned short* gp = H3 + (size_t)ga * 128 + cg * 8;
        __builtin_amdgcn_global_load_lds(
            (const __attribute__((address_space(1))) void*)gp,
            (__attribute__((address_space(3))) void*)&Asl[(size_t)s * 8], 16, 0, 0);
    }
#pragma unroll
    for (int it = 0; it < 4; it++) {
        int s = it * 256 + tid;
        int r = it * 16 + r0;
        const unsigned short* gp = W1t + (size_t)r * 128 + cg * 8;
        __builtin_amdgcn_global_load_lds(
            (const __attribute__((address_space(1))) void*)gp,
            (__attribute__((address_space(3))) void*)&Bsl[(size_t)s * 8], 16, 0, 0);
    }
    __syncthreads();

    const int wm = wave * 32;
    f32x4 acc[2][4] = {};
#pragma unroll
    for (int kh = 0; kh < 4; kh++) {
        bf16x8 af[2], bfv[4];
#pragma unroll
        for (int mi = 0; mi < 2; mi++) {
            int row = wm + mi * 16 + l16;
            int ch = (kh * 4 + q) ^ (row & 7);
            af[mi] = *reinterpret_cast<const bf16x8*>(&Asl[row * 128 + ch * 8]);
        }
#pragma unroll
        for (int ni = 0; ni < 4; ni++) {
            int row = ni * 16 + l16;
            int ch = (kh * 4 + q) ^ (row & 7);
            bfv[ni] = *reinterpret_cast<const bf16x8*>(&Bsl[row * 128 + ch * 8]);
        }
#pragma unroll
        for (int mi = 0; mi < 2; mi++)
#pragma unroll
            for (int ni = 0; ni < 4; ni++)
                acc[mi][ni] = __builtin_amdgcn_mfma_f32_16x16x32_bf16(af[mi], bfv[ni], acc[mi][ni], 0, 0, 0);
    }
    __syncthreads();

    float b1v[4], w2v[4];
#pragma unroll
    for (int ni = 0; ni < 4; ni++) {
        int cI = ni * 16 + l16;
        b1v[ni] = bs1[cI];
        w2v[ni] = Ws2[cI];
    }
    float* red = reinterpret_cast<float*>(Bsl);
#pragma unroll
    for (int mi = 0; mi < 2; mi++) {
#pragma unroll
        for (int r = 0; r < 4; r++) {
            int lrow = wm + mi * 16 + q * 4 + r;
            float p = 0.f;
#pragma unroll
            for (int ni = 0; ni < 4; ni++)
                p += fmaxf(acc[mi][ni][r] + b1v[ni], 0.f) * w2v[ni];
#pragma unroll
            for (int d = 1; d < 16; d <<= 1) p += __shfl_xor(p, d);
            if (l16 == 0) red[lrow] = p;
        }
    }
    __syncthreads();
    if (tid < 128) {
        int g = rowBase + tid;
        if (g < M) out[g] = 1.f / (1.f + __expf(-(red[tid] + bs2[0])));
    }
}

// ---------------- launch ----------------
extern "C" void kernel_launch(void* const* d_in, const int* in_sizes, int n_in,
                              void* d_out, int out_size, void* d_ws, size_t ws_size,
                              hipStream_t stream) {
    const float* x   = (const float*)d_in[0];
    const int*   ei  = (const int*)d_in[1];
    const float* W1  = (const float*)d_in[2];
    const float* as1 = (const float*)d_in[3];
    const float* ad1 = (const float*)d_in[4];
    const float* b1  = (const float*)d_in[5];
    const float* W2  = (const float*)d_in[6];
    const float* as2 = (const float*)d_in[7];
    const float* ad2 = (const float*)d_in[8];
    const float* b2  = (const float*)d_in[9];
    const float* W3  = (const float*)d_in[10];
    const float* as3 = (const float*)d_in[11];
    const float* ad3 = (const float*)d_in[12];
    const float* b3  = (const float*)d_in[13];
    const float* Ws1 = (const float*)d_in[14];
    const float* bs1 = (const float*)d_in[15];
    const float* Ws2 = (const float*)d_in[16];
    const float* bs2 = (const float*)d_in[17];

    const int N = out_size;            // 20000
    const int E = in_sizes[1] / 2;     // 160000
    const int D = in_sizes[0] / N;     // 768
    const int HC = 512, H = 4, C = 128;
    const int Etot = E + N;

    char* p = (char*)d_ws;
    auto alloc = [&](size_t bytes) -> void* {
        void* q = (void*)p;
        p += (bytes + 255) & ~(size_t)255;
        return q;
    };
    char*  zbeg   = p;
    int*   deg    = (int*)alloc((size_t)N * 4);
    int*   cursor = (int*)alloc((size_t)N * 4);
    char*  zend   = p;
    float* alS1   = (float*)alloc((size_t)N * H * 4);
    float* alD1   = (float*)alloc((size_t)N * H * 4);
    float* alS2   = (float*)alloc((size_t)N * H * 4);
    float* alD2   = (float*)alloc((size_t)N * H * 4);
    float* alS3   = (float*)alloc((size_t)N * 4);
    float* alD3   = (float*)alloc((size_t)N * 4);
    int*   off    = (int*)alloc((size_t)(N + 1) * 4);
    int*   csr    = (int*)alloc((size_t)Etot * 4);
    unsigned short* hbuf = (unsigned short*)alloc((size_t)N * HC * 2);
    unsigned short* xbf  = (unsigned short*)alloc((size_t)N * D * 2);   // reused as h3 bf16
    unsigned short* obf  = (unsigned short*)alloc((size_t)N * HC * 2);
    unsigned short* W1t  = (unsigned short*)alloc((size_t)D * HC * 2);
    unsigned short* W2t  = (unsigned short*)alloc((size_t)HC * HC * 2);
    unsigned short* W3t  = (unsigned short*)alloc((size_t)HC * C * 2);
    unsigned short* Ws1t = (unsigned short*)alloc((size_t)C * 64 * 2);

    hipMemsetAsync(zbeg, 0, (size_t)(zend - zbeg), stream);

    // ---- fused preprocessing (cast + transposes + degree count) ----
    {
        int n4 = N * D / 4;
        int c0 = (n4 + 255) / 256;
        int c1 = (D * HC + 255) / 256;
        int c2 = (HC * HC + 255) / 256;
        int c3 = (HC * C + 255) / 256;
        int c4 = (128 * 64 + 255) / 256;
        int c5 = (Etot + 255) / 256;
        int total = c0 + c1 + c2 + c3 + c4 + c5;
        preproc_kernel<<<total, 256, 0, stream>>>(
            x, xbf, n4, W1, W1t, W2, W2t, W3, W3t, Ws1, Ws1t,
            ei, E, N, deg, c0, c1, c2, c3, c4, D, HC, C);
    }
    scan_kernel<<<1, 1024, 0, stream>>>(deg, off, N);

    int node_blocks = (N + 3) / 4;       // one wave per node
    int rowTiles64 = (N + 63) / 64;      // BM=64 -> 313
    int headTiles = (N + 127) / 128;     // 157
    int scatBlocks = (Etot + 255) / 256;

    // ---- layer 1 (scatter fused into same dispatch) ----
    gemm_bf16_alpha<4><<<scatBlocks + rowTiles64 * 4, 256, 0, stream>>>(
        xbf, W1t, hbuf, N, HC, D, rowTiles64, as1, ad1, alS1, alD1,
        scatBlocks, ei, E, off, cursor, csr);
    gat_aggregate<4, 128, 0><<<node_blocks, 256, 0, stream>>>(
        hbuf, alS1, alD1, off, csr, b1, obf, N);

    // ---- layer 2 ----
    gemm_bf16_alpha<4><<<rowTiles64 * 4, 256, 0, stream>>>(
        obf, W2t, hbuf, N, HC, HC, rowTiles64, as2, ad2, alS2, alD2,
        0, nullptr, 0, nullptr, nullptr, nullptr);
    gat_aggregate<4, 128, 0><<<node_blocks, 256, 0, stream>>>(
        hbuf, alS2, alD2, off, csr, b2, obf, N);

    // ---- layer 3 (H=1): aggregate -> h3 bf16 (bias, no relu) ----
    gemm_bf16_alpha<1><<<rowTiles64, 256, 0, stream>>>(
        obf, W3t, hbuf, N, C, HC, rowTiles64, as3, ad3, alS3, alD3,
        0, nullptr, 0, nullptr, nullptr, nullptr);
    gat_aggregate<1, 128, 2><<<node_blocks, 256, 0, stream>>>(
        hbuf, alS3, alD3, off, csr, b3, xbf, N);

    // ---- MFMA risk head ----
    head_mfma<<<headTiles, 256, 0, stream>>>(xbf, Ws1t, bs1, Ws2, bs2, (float*)d_out, N);
}